// Round 1
// baseline (2676.327 us; speedup 1.0000x reference)
//
#include <hip/hip_runtime.h>
#include <cmath>

#define BB    2
#define LSEQ  1024
#define DM    512
#define DI    1024
#define NTOK  2048   // BB*LSEQ

__device__ __forceinline__ float siluf(float x) {
    return x * (1.0f / (1.0f + __expf(-x)));
}

__device__ __forceinline__ float geluf(float x) {
    // JAX default gelu: approximate=True (tanh form)
    float c = 0.7978845608028654f * (x + 0.044715f * x * x * x);
    return 0.5f * x * (1.0f + tanhf(c));
}

// ---------------- LayerNorm: one block (256 thr) per token, D=512 ----------------
__global__ void ln_kernel(const float* __restrict__ x, const float* __restrict__ g,
                          const float* __restrict__ b, float* __restrict__ out)
{
    int t = blockIdx.x;
    int tid = threadIdx.x;
    const float* xr = x + (size_t)t * DM;
    float v0 = xr[tid];
    float v1 = xr[tid + 256];
    float s  = v0 + v1;
    float s2 = v0 * v0 + v1 * v1;
    #pragma unroll
    for (int o = 32; o > 0; o >>= 1) { s += __shfl_down(s, o); s2 += __shfl_down(s2, o); }
    __shared__ float sh[4], sh2[4];
    __shared__ float smu, srs;
    int wid = tid >> 6, lane = tid & 63;
    if (lane == 0) { sh[wid] = s; sh2[wid] = s2; }
    __syncthreads();
    if (tid == 0) {
        float a  = sh[0] + sh[1] + sh[2] + sh[3];
        float a2 = sh2[0] + sh2[1] + sh2[2] + sh2[3];
        float mu = a / DM;
        float var = a2 / DM - mu * mu;
        smu = mu;
        srs = rsqrtf(var + 1e-5f);
    }
    __syncthreads();
    float mu = smu, rs = srs;
    float* orow = out + (size_t)t * DM;
    orow[tid]       = (v0 - mu) * rs * g[tid]       + b[tid];
    orow[tid + 256] = (v1 - mu) * rs * g[tid + 256] + b[tid + 256];
}

// ---------------- GEMM: C[m,n] = epi( sum_k A[m,k] * W[n,k] ) ----------------
// W is [N,K] row-major (all reference einsums are x @ W^T).
// EPI: 0 plain, 1 bias+softplus, 2 bias+gelu, 3 residual, 4 bias+residual
template<int EPI>
__global__ __launch_bounds__(1024)
void gemm_kernel(const float* __restrict__ A, int lda,
                 const float* __restrict__ W, int K,
                 float* __restrict__ C, int ldc,
                 const float* __restrict__ bias,
                 const float* __restrict__ resid, int ldr)
{
    __shared__ float As[32][33];
    __shared__ float Ws[32][33];
    int tx = threadIdx.x, ty = threadIdx.y;
    int m0 = blockIdx.y * 32, n0 = blockIdx.x * 32;
    float acc = 0.0f;
    for (int k0 = 0; k0 < K; k0 += 32) {
        As[ty][tx] = A[(size_t)(m0 + ty) * lda + k0 + tx];
        Ws[ty][tx] = W[(size_t)(n0 + ty) * K  + k0 + tx];
        __syncthreads();
        #pragma unroll
        for (int kk = 0; kk < 32; ++kk)
            acc = fmaf(As[ty][kk], Ws[tx][kk], acc);
        __syncthreads();
    }
    int m = m0 + ty, n = n0 + tx;
    float v = acc;
    if (EPI == 1) { v += bias[n]; v = (v < 20.0f) ? log1pf(__expf(v)) : v; }
    if (EPI == 2) { v += bias[n]; v = geluf(v); }
    if (EPI == 3) { v += resid[(size_t)m * ldr + n]; }
    if (EPI == 4) { v += bias[n] + resid[(size_t)m * ldr + n]; }
    C[(size_t)m * ldc + n] = v;
}

// ---------------- depthwise causal conv1d (width 4) + SiLU ----------------
// xi = first DI columns of xz (row stride 2048)
__global__ void conv_silu_kernel(const float* __restrict__ xz,
                                 const float* __restrict__ cw,
                                 const float* __restrict__ cb,
                                 float* __restrict__ xc)
{
    int idx = blockIdx.x * 256 + threadIdx.x;   // over NTOK*DI
    int e = idx & (DI - 1);
    int t = idx >> 10;                          // token index b*L + l
    int l = t & (LSEQ - 1);
    float w0 = cw[e * 4 + 0], w1 = cw[e * 4 + 1], w2 = cw[e * 4 + 2], w3 = cw[e * 4 + 3];
    float acc = cb[e];
    const float* base = xz + (size_t)t * 2048 + e;
    if (l >= 3) acc = fmaf(base[-3 * 2048], w0, acc);
    if (l >= 2) acc = fmaf(base[-2 * 2048], w1, acc);
    if (l >= 1) acc = fmaf(base[-1 * 2048], w2, acc);
    acc = fmaf(base[0], w3, acc);
    xc[idx] = siluf(acc);
}

// ---------------- selective-scan: one thread per (b,e), 16 states in regs ----------------
__global__ void scan_kernel(const float* __restrict__ delta,
                            const float* __restrict__ xc,
                            const float* __restrict__ xdbl,   // [NTOK,64]: dt|B|C
                            const float* __restrict__ xz,     // z at col offset DI
                            const float* __restrict__ A_log,
                            const float* __restrict__ Dp,
                            float* __restrict__ y)
{
    int t = blockIdx.x * 256 + threadIdx.x;     // 0..2047
    int b = t >> 10;
    int e = t & (DI - 1);
    float Ae[16], h[16];
    #pragma unroll
    for (int n = 0; n < 16; ++n) { Ae[n] = -__expf(A_log[e * 16 + n]); h[n] = 0.0f; }
    float Dv = Dp[e];
    for (int l = 0; l < LSEQ; ++l) {
        size_t tok = (size_t)b * LSEQ + l;
        float d   = delta[tok * DI + e];
        float xcv = xc[tok * DI + e];
        float zv  = xz[tok * 2048 + DI + e];
        const float4* B4 = (const float4*)(xdbl + tok * 64 + 32);
        const float4* C4 = (const float4*)(xdbl + tok * 64 + 48);
        float yv = 0.0f;
        #pragma unroll
        for (int q = 0; q < 4; ++q) {
            float4 Bq = B4[q];
            float4 Cq = C4[q];
            float hb;
            hb = __expf(d * Ae[4*q+0]) * h[4*q+0] + d * Bq.x * xcv; h[4*q+0] = hb; yv = fmaf(hb, Cq.x, yv);
            hb = __expf(d * Ae[4*q+1]) * h[4*q+1] + d * Bq.y * xcv; h[4*q+1] = hb; yv = fmaf(hb, Cq.y, yv);
            hb = __expf(d * Ae[4*q+2]) * h[4*q+2] + d * Bq.z * xcv; h[4*q+2] = hb; yv = fmaf(hb, Cq.z, yv);
            hb = __expf(d * Ae[4*q+3]) * h[4*q+3] + d * Bq.w * xcv; h[4*q+3] = hb; yv = fmaf(hb, Cq.w, yv);
        }
        yv += xcv * Dv;
        yv *= siluf(zv);
        y[tok * DI + e] = yv;
    }
}

extern "C" void kernel_launch(void* const* d_in, const int* in_sizes, int n_in,
                              void* d_out, int out_size, void* d_ws, size_t ws_size,
                              hipStream_t stream)
{
    const float* x         = (const float*)d_in[0];
    const float* ln1_g     = (const float*)d_in[1];
    const float* ln1_b     = (const float*)d_in[2];
    const float* in_proj_w = (const float*)d_in[3];
    const float* conv_w    = (const float*)d_in[4];
    const float* conv_b    = (const float*)d_in[5];
    const float* x_proj_w  = (const float*)d_in[6];
    const float* dt_proj_w = (const float*)d_in[7];
    const float* dt_proj_b = (const float*)d_in[8];
    const float* A_log     = (const float*)d_in[9];
    const float* Dp        = (const float*)d_in[10];
    const float* out_proj_w= (const float*)d_in[11];
    const float* ln2_g     = (const float*)d_in[12];
    const float* ln2_b     = (const float*)d_in[13];
    const float* ffn1_w    = (const float*)d_in[14];
    const float* ffn1_b    = (const float*)d_in[15];
    const float* ffn2_w    = (const float*)d_in[16];
    const float* ffn2_b    = (const float*)d_in[17];
    float* out = (float*)d_out;

    float* ws = (float*)d_ws;
    float* buf_ln    = ws;                        // 2048*512
    float* buf_xz    = buf_ln    + 2048 * 512;    // 2048*2048 (xi | z); reused as ffn_mid
    float* buf_xc    = buf_xz    + 2048 * 2048;   // 2048*1024
    float* buf_xdbl  = buf_xc    + 2048 * 1024;   // 2048*64 (dt|B|C)
    float* buf_delta = buf_xdbl  + 2048 * 64;     // 2048*1024
    float* buf_y     = buf_delta + 2048 * 1024;   // 2048*1024
    float* buf_x2    = buf_y     + 2048 * 1024;   // 2048*512

    dim3 blk(32, 32);

    // 1) LN1
    ln_kernel<<<NTOK, 256, 0, stream>>>(x, ln1_g, ln1_b, buf_ln);
    // 2) in_proj: [2048,512] @ [2048,512]^T -> [2048,2048]
    gemm_kernel<0><<<dim3(2048/32, 2048/32), blk, 0, stream>>>(buf_ln, 512, in_proj_w, 512, buf_xz, 2048, nullptr, nullptr, 0);
    // 3) conv + silu -> xc
    conv_silu_kernel<<<(NTOK * DI) / 256, 256, 0, stream>>>(buf_xz, conv_w, conv_b, buf_xc);
    // 4) x_proj: [2048,1024] @ [64,1024]^T -> [2048,64]
    gemm_kernel<0><<<dim3(64/32, 2048/32), blk, 0, stream>>>(buf_xc, 1024, x_proj_w, 1024, buf_xdbl, 64, nullptr, nullptr, 0);
    // 5) dt_proj + softplus: [2048,32] @ [1024,32]^T -> [2048,1024]
    gemm_kernel<1><<<dim3(1024/32, 2048/32), blk, 0, stream>>>(buf_xdbl, 64, dt_proj_w, 32, buf_delta, 1024, dt_proj_b, nullptr, 0);
    // 6) selective scan (+ xc*D, * silu(z))
    scan_kernel<<<NTOK / 256, 256, 0, stream>>>(buf_delta, buf_xc, buf_xdbl, buf_xz, A_log, Dp, buf_y);
    // 7) out_proj + residual: [2048,1024] @ [512,1024]^T + x -> x2
    gemm_kernel<3><<<dim3(512/32, 2048/32), blk, 0, stream>>>(buf_y, 1024, out_proj_w, 1024, buf_x2, 512, nullptr, x, 512);
    // 8) LN2
    ln_kernel<<<NTOK, 256, 0, stream>>>(buf_x2, ln2_g, ln2_b, buf_ln);
    // 9) ffn1 + gelu: [2048,512] @ [2048,512]^T -> [2048,2048]
    gemm_kernel<2><<<dim3(2048/32, 2048/32), blk, 0, stream>>>(buf_ln, 512, ffn1_w, 512, buf_xz, 2048, ffn1_b, nullptr, 0);
    // 10) ffn2 + bias + residual -> out
    gemm_kernel<4><<<dim3(512/32, 2048/32), blk, 0, stream>>>(buf_xz, 2048, ffn2_w, 2048, out, 512, ffn2_b, buf_x2, 512);
}

// Round 2
// 1064.475 us; speedup vs baseline: 2.5142x; 2.5142x over previous
//
#include <hip/hip_runtime.h>
#include <cmath>

#define BB    2
#define LSEQ  1024
#define DM    512
#define DI    1024
#define NTOK  2048   // BB*LSEQ
#define NC    32     // chunks per sequence
#define CL    32     // chunk length (NC*CL == LSEQ)

__device__ __forceinline__ float siluf(float x) {
    return x * (1.0f / (1.0f + __expf(-x)));
}

__device__ __forceinline__ float geluf(float x) {
    // JAX default gelu: approximate=True (tanh form)
    float c = 0.7978845608028654f * (x + 0.044715f * x * x * x);
    return 0.5f * x * (1.0f + tanhf(c));
}

// ---------------- LayerNorm: one block (256 thr) per token, D=512 ----------------
__global__ void ln_kernel(const float* __restrict__ x, const float* __restrict__ g,
                          const float* __restrict__ b, float* __restrict__ out)
{
    int t = blockIdx.x;
    int tid = threadIdx.x;
    const float* xr = x + (size_t)t * DM;
    float v0 = xr[tid];
    float v1 = xr[tid + 256];
    float s  = v0 + v1;
    float s2 = v0 * v0 + v1 * v1;
    #pragma unroll
    for (int o = 32; o > 0; o >>= 1) { s += __shfl_down(s, o); s2 += __shfl_down(s2, o); }
    __shared__ float sh[4], sh2[4];
    __shared__ float smu, srs;
    int wid = tid >> 6, lane = tid & 63;
    if (lane == 0) { sh[wid] = s; sh2[wid] = s2; }
    __syncthreads();
    if (tid == 0) {
        float a  = sh[0] + sh[1] + sh[2] + sh[3];
        float a2 = sh2[0] + sh2[1] + sh2[2] + sh2[3];
        float mu = a / DM;
        float var = a2 / DM - mu * mu;
        smu = mu;
        srs = rsqrtf(var + 1e-5f);
    }
    __syncthreads();
    float mu = smu, rs = srs;
    float* orow = out + (size_t)t * DM;
    orow[tid]       = (v0 - mu) * rs * g[tid]       + b[tid];
    orow[tid + 256] = (v1 - mu) * rs * g[tid + 256] + b[tid + 256];
}

// ---------------- GEMM: C[m,n] = epi( sum_k A[m,k] * W[n,k] ) ----------------
// W is [N,K] row-major (all reference einsums are x @ W^T).
// EPI: 0 plain, 1 bias+softplus, 2 bias+gelu, 3 residual, 4 bias+residual
template<int EPI>
__global__ __launch_bounds__(1024)
void gemm_kernel(const float* __restrict__ A, int lda,
                 const float* __restrict__ W, int K,
                 float* __restrict__ C, int ldc,
                 const float* __restrict__ bias,
                 const float* __restrict__ resid, int ldr)
{
    __shared__ float As[32][33];
    __shared__ float Ws[32][33];
    int tx = threadIdx.x, ty = threadIdx.y;
    int m0 = blockIdx.y * 32, n0 = blockIdx.x * 32;
    float acc = 0.0f;
    for (int k0 = 0; k0 < K; k0 += 32) {
        As[ty][tx] = A[(size_t)(m0 + ty) * lda + k0 + tx];
        Ws[ty][tx] = W[(size_t)(n0 + ty) * K  + k0 + tx];
        __syncthreads();
        #pragma unroll
        for (int kk = 0; kk < 32; ++kk)
            acc = fmaf(As[ty][kk], Ws[tx][kk], acc);
        __syncthreads();
    }
    int m = m0 + ty, n = n0 + tx;
    float v = acc;
    if (EPI == 1) { v += bias[n]; v = (v < 20.0f) ? log1pf(__expf(v)) : v; }
    if (EPI == 2) { v += bias[n]; v = geluf(v); }
    if (EPI == 3) { v += resid[(size_t)m * ldr + n]; }
    if (EPI == 4) { v += bias[n] + resid[(size_t)m * ldr + n]; }
    C[(size_t)m * ldc + n] = v;
}

// ---------------- depthwise causal conv1d (width 4) + SiLU ----------------
__global__ void conv_silu_kernel(const float* __restrict__ xz,
                                 const float* __restrict__ cw,
                                 const float* __restrict__ cb,
                                 float* __restrict__ xc)
{
    int idx = blockIdx.x * 256 + threadIdx.x;   // over NTOK*DI
    int e = idx & (DI - 1);
    int t = idx >> 10;                          // token index b*L + l
    int l = t & (LSEQ - 1);
    float w0 = cw[e * 4 + 0], w1 = cw[e * 4 + 1], w2 = cw[e * 4 + 2], w3 = cw[e * 4 + 3];
    float acc = cb[e];
    const float* base = xz + (size_t)t * 2048 + e;
    if (l >= 3) acc = fmaf(base[-3 * 2048], w0, acc);
    if (l >= 2) acc = fmaf(base[-2 * 2048], w1, acc);
    if (l >= 1) acc = fmaf(base[-1 * 2048], w2, acc);
    acc = fmaf(base[0], w3, acc);
    xc[idx] = siluf(acc);
}

// ============ chunked selective scan ============
// Pass A: per (b,e,chunk): local scan from h=0 -> q[16]; also sum(delta).
__global__ void scanA_kernel(const float* __restrict__ delta,
                             const float* __restrict__ xc,
                             const float* __restrict__ xdbl,
                             const float* __restrict__ A_log,
                             float* __restrict__ qbuf,
                             float* __restrict__ sumd)
{
    int i = blockIdx.x * 256 + threadIdx.x;   // ((b*NC + c) << 10) | e
    int e = i & (DI - 1);
    int c = (i >> 10) & (NC - 1);
    int b = i >> 15;
    float Ae[16], h[16];
    #pragma unroll
    for (int n = 0; n < 16; ++n) { Ae[n] = -__expf(A_log[e * 16 + n]); h[n] = 0.0f; }
    float sd = 0.0f;
    int l0 = c * CL;
    for (int l = 0; l < CL; ++l) {
        size_t tok = (size_t)b * LSEQ + l0 + l;
        float d   = delta[tok * DI + e];
        float xcv = xc[tok * DI + e];
        sd += d;
        float dx = d * xcv;
        const float4* B4 = (const float4*)(xdbl + tok * 64 + 32);
        #pragma unroll
        for (int q = 0; q < 4; ++q) {
            float4 Bq = B4[q];
            h[4*q+0] = __expf(d * Ae[4*q+0]) * h[4*q+0] + dx * Bq.x;
            h[4*q+1] = __expf(d * Ae[4*q+1]) * h[4*q+1] + dx * Bq.y;
            h[4*q+2] = __expf(d * Ae[4*q+2]) * h[4*q+2] + dx * Bq.z;
            h[4*q+3] = __expf(d * Ae[4*q+3]) * h[4*q+3] + dx * Bq.w;
        }
    }
    size_t base = ((size_t)(b * DI + e) * NC + c) * 16;
    #pragma unroll
    for (int n = 0; n < 16; ++n) qbuf[base + n] = h[n];
    sumd[(size_t)(b * DI + e) * NC + c] = sd;
}

// Pass B: per (b,e,n): combine chunks sequentially; store entry state per chunk.
__global__ void scanB_kernel(const float* __restrict__ qbuf,
                             const float* __restrict__ sumd,
                             const float* __restrict__ A_log,
                             float* __restrict__ hin)
{
    int i = blockIdx.x * 256 + threadIdx.x;   // ((b<<10)|e)<<4 | n
    int n = i & 15;
    int e = (i >> 4) & (DI - 1);
    int b = i >> 14;
    float Ae = -__expf(A_log[e * 16 + n]);
    float h = 0.0f;
    size_t base = (size_t)(b * DI + e) * NC;
    for (int c = 0; c < NC; ++c) {
        hin[(base + c) * 16 + n] = h;
        float P = __expf(Ae * sumd[base + c]);
        h = P * h + qbuf[(base + c) * 16 + n];
    }
}

// Pass C: per (b,e,chunk): replay from true entry state, emit y (+D skip, *silu(z)).
// NOTE: y may alias delta (each element is read before being overwritten by the
// same thread) -- no __restrict__ on those two.
__global__ void scanC_kernel(const float* delta,
                             const float* __restrict__ xc,
                             const float* __restrict__ xdbl,
                             const float* __restrict__ xz,
                             const float* __restrict__ A_log,
                             const float* __restrict__ Dp,
                             const float* __restrict__ hin,
                             float* y)
{
    int i = blockIdx.x * 256 + threadIdx.x;
    int e = i & (DI - 1);
    int c = (i >> 10) & (NC - 1);
    int b = i >> 15;
    float Ae[16], h[16];
    size_t base = ((size_t)(b * DI + e) * NC + c) * 16;
    #pragma unroll
    for (int n = 0; n < 16; ++n) {
        Ae[n] = -__expf(A_log[e * 16 + n]);
        h[n] = hin[base + n];
    }
    float Dv = Dp[e];
    int l0 = c * CL;
    for (int l = 0; l < CL; ++l) {
        size_t tok = (size_t)b * LSEQ + l0 + l;
        float d   = delta[tok * DI + e];
        float xcv = xc[tok * DI + e];
        float zv  = xz[tok * 2048 + DI + e];
        float dx = d * xcv;
        const float4* B4 = (const float4*)(xdbl + tok * 64 + 32);
        const float4* C4 = (const float4*)(xdbl + tok * 64 + 48);
        float yv = 0.0f;
        #pragma unroll
        for (int q = 0; q < 4; ++q) {
            float4 Bq = B4[q];
            float4 Cq = C4[q];
            float hb;
            hb = __expf(d * Ae[4*q+0]) * h[4*q+0] + dx * Bq.x; h[4*q+0] = hb; yv = fmaf(hb, Cq.x, yv);
            hb = __expf(d * Ae[4*q+1]) * h[4*q+1] + dx * Bq.y; h[4*q+1] = hb; yv = fmaf(hb, Cq.y, yv);
            hb = __expf(d * Ae[4*q+2]) * h[4*q+2] + dx * Bq.z; h[4*q+2] = hb; yv = fmaf(hb, Cq.z, yv);
            hb = __expf(d * Ae[4*q+3]) * h[4*q+3] + dx * Bq.w; h[4*q+3] = hb; yv = fmaf(hb, Cq.w, yv);
        }
        yv += xcv * Dv;
        yv *= siluf(zv);
        y[tok * DI + e] = yv;
    }
}

extern "C" void kernel_launch(void* const* d_in, const int* in_sizes, int n_in,
                              void* d_out, int out_size, void* d_ws, size_t ws_size,
                              hipStream_t stream)
{
    const float* x         = (const float*)d_in[0];
    const float* ln1_g     = (const float*)d_in[1];
    const float* ln1_b     = (const float*)d_in[2];
    const float* in_proj_w = (const float*)d_in[3];
    const float* conv_w    = (const float*)d_in[4];
    const float* conv_b    = (const float*)d_in[5];
    const float* x_proj_w  = (const float*)d_in[6];
    const float* dt_proj_w = (const float*)d_in[7];
    const float* dt_proj_b = (const float*)d_in[8];
    const float* A_log     = (const float*)d_in[9];
    const float* Dp        = (const float*)d_in[10];
    const float* out_proj_w= (const float*)d_in[11];
    const float* ln2_g     = (const float*)d_in[12];
    const float* ln2_b     = (const float*)d_in[13];
    const float* ffn1_w    = (const float*)d_in[14];
    const float* ffn1_b    = (const float*)d_in[15];
    const float* ffn2_w    = (const float*)d_in[16];
    const float* ffn2_b    = (const float*)d_in[17];
    float* out = (float*)d_out;

    float* ws = (float*)d_ws;
    float* buf_ln    = ws;                        // 2048*512
    float* buf_xz    = buf_ln    + 2048 * 512;    // 2048*2048 (xi | z); reused as ffn_mid
    float* buf_xc    = buf_xz    + 2048 * 2048;   // 2048*1024
    float* buf_xdbl  = buf_xc    + 2048 * 1024;   // 2048*64 (dt|B|C)
    float* buf_delta = buf_xdbl  + 2048 * 64;     // 2048*1024
    float* buf_y     = buf_delta;                 // ALIAS: y overwrites delta in scanC
    float* buf_q     = buf_delta + 2048 * 1024;   // 2048*NC*16 = 1M floats
    float* buf_hin   = buf_q     + 2048 * NC*16;  // 1M floats
    float* buf_x2    = buf_hin   + 2048 * NC*16;  // 2048*512
    float* buf_sumd  = buf_ln;                    // ALIAS: ln buffer idle between steps 3-7

    dim3 blk(32, 32);

    // 1) LN1
    ln_kernel<<<NTOK, 256, 0, stream>>>(x, ln1_g, ln1_b, buf_ln);
    // 2) in_proj: [2048,512] @ [2048,512]^T -> [2048,2048]
    gemm_kernel<0><<<dim3(2048/32, 2048/32), blk, 0, stream>>>(buf_ln, 512, in_proj_w, 512, buf_xz, 2048, nullptr, nullptr, 0);
    // 3) conv + silu -> xc
    conv_silu_kernel<<<(NTOK * DI) / 256, 256, 0, stream>>>(buf_xz, conv_w, conv_b, buf_xc);
    // 4) x_proj: [2048,1024] @ [64,1024]^T -> [2048,64]
    gemm_kernel<0><<<dim3(64/32, 2048/32), blk, 0, stream>>>(buf_xc, 1024, x_proj_w, 1024, buf_xdbl, 64, nullptr, nullptr, 0);
    // 5) dt_proj + softplus: [2048,32] @ [1024,32]^T -> [2048,1024]
    gemm_kernel<1><<<dim3(1024/32, 2048/32), blk, 0, stream>>>(buf_xdbl, 64, dt_proj_w, 32, buf_delta, 1024, dt_proj_b, nullptr, 0);
    // 6) chunked selective scan
    scanA_kernel<<<(BB * NC * DI) / 256, 256, 0, stream>>>(buf_delta, buf_xc, buf_xdbl, A_log, buf_q, buf_sumd);
    scanB_kernel<<<(BB * DI * 16) / 256, 256, 0, stream>>>(buf_q, buf_sumd, A_log, buf_hin);
    scanC_kernel<<<(BB * NC * DI) / 256, 256, 0, stream>>>(buf_delta, buf_xc, buf_xdbl, buf_xz, A_log, Dp, buf_hin, buf_y);
    // 7) out_proj + residual: [2048,1024] @ [512,1024]^T + x -> x2
    gemm_kernel<3><<<dim3(512/32, 2048/32), blk, 0, stream>>>(buf_y, 1024, out_proj_w, 1024, buf_x2, 512, nullptr, x, 512);
    // 8) LN2
    ln_kernel<<<NTOK, 256, 0, stream>>>(buf_x2, ln2_g, ln2_b, buf_ln);
    // 9) ffn1 + gelu: [2048,512] @ [2048,512]^T -> [2048,2048]
    gemm_kernel<2><<<dim3(2048/32, 2048/32), blk, 0, stream>>>(buf_ln, 512, ffn1_w, 512, buf_xz, 2048, ffn1_b, nullptr, 0);
    // 10) ffn2 + bias + residual -> out
    gemm_kernel<4><<<dim3(512/32, 2048/32), blk, 0, stream>>>(buf_xz, 2048, ffn2_w, 2048, out, 512, ffn2_b, buf_x2, 512);
}

// Round 3
// 242.511 us; speedup vs baseline: 11.0359x; 4.3894x over previous
//
#include <hip/hip_runtime.h>
#include <cmath>

typedef unsigned short u16;
typedef __attribute__((ext_vector_type(8))) short bf16x8;
typedef __attribute__((ext_vector_type(4))) float f32x4;

#define BB    2
#define LSEQ  1024
#define DM    512
#define DI    1024
#define NTOK  2048   // BB*LSEQ
#define NC    32     // chunks per sequence
#define CL    32     // chunk length

__device__ __forceinline__ float siluf(float x) {
    return x * (1.0f / (1.0f + __expf(-x)));
}
__device__ __forceinline__ float geluf(float x) {
    float c = 0.7978845608028654f * (x + 0.044715f * x * x * x);
    return 0.5f * x * (1.0f + tanhf(c));
}
__device__ __forceinline__ u16 f2bf(float f) {
    union { float f; unsigned u; } v; v.f = f;
    unsigned r = v.u + 0x7fff + ((v.u >> 16) & 1);
    return (u16)(r >> 16);
}
__device__ __forceinline__ float bf2f(u16 u) {
    union { unsigned u; float f; } v; v.u = ((unsigned)u) << 16; return v.f;
}
__device__ __forceinline__ void async_cp16(const u16* g, u16* l) {
    __builtin_amdgcn_global_load_lds(
        (const __attribute__((address_space(1))) void*)g,
        (__attribute__((address_space(3))) void*)l, 16, 0, 0);
}

// ---------------- fp32 -> bf16 conversion ----------------
__global__ void cvt_bf16_kernel(const float* __restrict__ in, u16* __restrict__ out, int n)
{
    int i = (blockIdx.x * 256 + threadIdx.x) * 4;
    if (i >= n) return;
    float4 v = *(const float4*)(in + i);
    ushort4 o;
    o.x = f2bf(v.x); o.y = f2bf(v.y); o.z = f2bf(v.z); o.w = f2bf(v.w);
    *(ushort4*)(out + i) = o;
}

// ---------------- LayerNorm: one block (256 thr) per token, D=512; bf16 out ----------------
__global__ void ln_bf16_kernel(const float* __restrict__ x, const float* __restrict__ g,
                               const float* __restrict__ b, u16* __restrict__ out)
{
    int t = blockIdx.x;
    int tid = threadIdx.x;
    const float* xr = x + (size_t)t * DM;
    float v0 = xr[tid];
    float v1 = xr[tid + 256];
    float s  = v0 + v1;
    float s2 = v0 * v0 + v1 * v1;
    #pragma unroll
    for (int o = 32; o > 0; o >>= 1) { s += __shfl_down(s, o); s2 += __shfl_down(s2, o); }
    __shared__ float sh[4], sh2[4];
    __shared__ float smu, srs;
    int wid = tid >> 6, lane = tid & 63;
    if (lane == 0) { sh[wid] = s; sh2[wid] = s2; }
    __syncthreads();
    if (tid == 0) {
        float a  = sh[0] + sh[1] + sh[2] + sh[3];
        float a2 = sh2[0] + sh2[1] + sh2[2] + sh2[3];
        float mu = a / DM;
        float var = a2 / DM - mu * mu;
        smu = mu;
        srs = rsqrtf(var + 1e-5f);
    }
    __syncthreads();
    float mu = smu, rs = srs;
    u16* orow = out + (size_t)t * DM;
    orow[tid]       = f2bf((v0 - mu) * rs * g[tid]       + b[tid]);
    orow[tid + 256] = f2bf((v1 - mu) * rs * g[tid + 256] + b[tid + 256]);
}

// ---------------- MFMA bf16 GEMM: C[m,n] = epi( sum_k A[m,k]*W[n,k] ) ----------------
// A [M,K] bf16 row-major, W [N,K] bf16 row-major. 4 waves (2x2), 16x16x32 MFMA.
// EPI: 0 plain, 2 bias+gelu, 3 +resid, 4 bias+resid.  OBF: bf16 output.
template<int EPI, int BM, int BN, int BK, int OBF>
__global__ __launch_bounds__(256)
void mgemm_kernel(const u16* __restrict__ A, const u16* __restrict__ W, int K,
                  void* __restrict__ Cp, int ldc,
                  const float* __restrict__ bias, const float* __restrict__ resid, int ldr)
{
    __shared__ u16 As[BM * BK];
    __shared__ u16 Bs[BN * BK];
    constexpr int WR = BM / 2, WC = BN / 2;
    constexpr int MR = WR / 16, NR = WC / 16;
    constexpr int LPR = BK / 8;            // lanes per staged row (16B each)
    constexpr int CH_ROWS = 64 / LPR;      // rows per 1KB chunk
    constexpr int NCH_A = BM / CH_ROWS, NCH_B = BN / CH_ROWS;

    const int tid = threadIdx.x;
    const int wave = tid >> 6, lane = tid & 63;
    const int wm = wave >> 1, wn = wave & 1;
    const int m0 = blockIdx.y * BM, n0 = blockIdx.x * BN;
    const int crow = lane / LPR, ckoff = (lane % LPR) * 8;
    const int fr = lane & 15;

    f32x4 acc[MR][NR] = {};

    for (int k0 = 0; k0 < K; k0 += BK) {
        for (int c = wave; c < NCH_A; c += 4) {
            const u16* g = A + (size_t)(m0 + c * CH_ROWS + crow) * K + k0 + ckoff;
            async_cp16(g, &As[c * 512]);
        }
        for (int c = wave; c < NCH_B; c += 4) {
            const u16* g = W + (size_t)(n0 + c * CH_ROWS + crow) * K + k0 + ckoff;
            async_cp16(g, &Bs[c * 512]);
        }
        __syncthreads();   // drains vmcnt (global_load_lds) for all waves
        #pragma unroll
        for (int ks = 0; ks < BK / 32; ++ks) {
            const int fk = ks * 32 + ((lane >> 4) << 3);
            bf16x8 af[MR], bv[NR];
            #pragma unroll
            for (int i = 0; i < MR; ++i)
                af[i] = *(const bf16x8*)&As[(wm * WR + i * 16 + fr) * BK + fk];
            #pragma unroll
            for (int j = 0; j < NR; ++j)
                bv[j] = *(const bf16x8*)&Bs[(wn * WC + j * 16 + fr) * BK + fk];
            #pragma unroll
            for (int i = 0; i < MR; ++i)
                #pragma unroll
                for (int j = 0; j < NR; ++j)
                    acc[i][j] = __builtin_amdgcn_mfma_f32_16x16x32_bf16(af[i], bv[j], acc[i][j], 0, 0, 0);
        }
        __syncthreads();
    }

    // C/D layout (m89-verified): col = lane&15, row = (lane>>4)*4 + reg
    const int rbase = (lane >> 4) << 2;
    #pragma unroll
    for (int i = 0; i < MR; ++i) {
        #pragma unroll
        for (int j = 0; j < NR; ++j) {
            const int col  = n0 + wn * WC + j * 16 + fr;
            const int row0 = m0 + wm * WR + i * 16 + rbase;
            float bvv = (EPI == 2 || EPI == 4) ? bias[col] : 0.0f;
            #pragma unroll
            for (int r = 0; r < 4; ++r) {
                float v = acc[i][j][r];
                if (EPI == 2) v = geluf(v + bvv);
                if (EPI == 3) v += resid[(size_t)(row0 + r) * ldr + col];
                if (EPI == 4) v += bvv + resid[(size_t)(row0 + r) * ldr + col];
                if (OBF) ((u16*)Cp)[(size_t)(row0 + r) * ldc + col] = f2bf(v);
                else     ((float*)Cp)[(size_t)(row0 + r) * ldc + col] = v;
            }
        }
    }
}

// ---------------- fp32 GEMM (small shapes: x_proj, dt_proj) ----------------
// EPI: 0 plain, 1 bias+softplus
template<int EPI>
__global__ __launch_bounds__(1024)
void gemm_kernel(const float* __restrict__ A, int lda,
                 const float* __restrict__ W, int K,
                 float* __restrict__ C, int ldc,
                 const float* __restrict__ bias)
{
    __shared__ float As[32][33];
    __shared__ float Ws[32][33];
    int tx = threadIdx.x, ty = threadIdx.y;
    int m0 = blockIdx.y * 32, n0 = blockIdx.x * 32;
    float acc = 0.0f;
    for (int k0 = 0; k0 < K; k0 += 32) {
        As[ty][tx] = A[(size_t)(m0 + ty) * lda + k0 + tx];
        Ws[ty][tx] = W[(size_t)(n0 + ty) * K  + k0 + tx];
        __syncthreads();
        #pragma unroll
        for (int kk = 0; kk < 32; ++kk)
            acc = fmaf(As[ty][kk], Ws[tx][kk], acc);
        __syncthreads();
    }
    int m = m0 + ty, n = n0 + tx;
    float v = acc;
    if (EPI == 1) { v += bias[n]; v = (v < 20.0f) ? log1pf(__expf(v)) : v; }
    C[(size_t)m * ldc + n] = v;
}

// ---------------- depthwise causal conv1d (width 4) + SiLU; bf16 in, fp32 out ----------------
__global__ void conv_silu_kernel(const u16* __restrict__ xz,
                                 const float* __restrict__ cw,
                                 const float* __restrict__ cb,
                                 float* __restrict__ xc)
{
    int idx = blockIdx.x * 256 + threadIdx.x;   // over NTOK*DI
    int e = idx & (DI - 1);
    int t = idx >> 10;
    int l = t & (LSEQ - 1);
    float w0 = cw[e * 4 + 0], w1 = cw[e * 4 + 1], w2 = cw[e * 4 + 2], w3 = cw[e * 4 + 3];
    float acc = cb[e];
    const u16* base = xz + (size_t)t * 2048 + e;
    if (l >= 3) acc = fmaf(bf2f(base[-3 * 2048]), w0, acc);
    if (l >= 2) acc = fmaf(bf2f(base[-2 * 2048]), w1, acc);
    if (l >= 1) acc = fmaf(bf2f(base[-1 * 2048]), w2, acc);
    acc = fmaf(bf2f(base[0]), w3, acc);
    xc[idx] = siluf(acc);
}

// ============ chunked selective scan ============
__global__ void scanA_kernel(const float* __restrict__ delta,
                             const float* __restrict__ xc,
                             const float* __restrict__ xdbl,
                             const float* __restrict__ A_log,
                             float* __restrict__ qbuf,
                             float* __restrict__ sumd)
{
    int i = blockIdx.x * 256 + threadIdx.x;   // ((b*NC + c) << 10) | e
    int e = i & (DI - 1);
    int c = (i >> 10) & (NC - 1);
    int b = i >> 15;
    float Ae[16], h[16];
    #pragma unroll
    for (int n = 0; n < 16; ++n) { Ae[n] = -__expf(A_log[e * 16 + n]); h[n] = 0.0f; }
    float sd = 0.0f;
    int l0 = c * CL;
    for (int l = 0; l < CL; ++l) {
        size_t tok = (size_t)b * LSEQ + l0 + l;
        float d   = delta[tok * DI + e];
        float xcv = xc[tok * DI + e];
        sd += d;
        float dx = d * xcv;
        const float4* B4 = (const float4*)(xdbl + tok * 64 + 32);
        #pragma unroll
        for (int q = 0; q < 4; ++q) {
            float4 Bq = B4[q];
            h[4*q+0] = __expf(d * Ae[4*q+0]) * h[4*q+0] + dx * Bq.x;
            h[4*q+1] = __expf(d * Ae[4*q+1]) * h[4*q+1] + dx * Bq.y;
            h[4*q+2] = __expf(d * Ae[4*q+2]) * h[4*q+2] + dx * Bq.z;
            h[4*q+3] = __expf(d * Ae[4*q+3]) * h[4*q+3] + dx * Bq.w;
        }
    }
    size_t base = ((size_t)(b * DI + e) * NC + c) * 16;
    #pragma unroll
    for (int n = 0; n < 16; ++n) qbuf[base + n] = h[n];
    sumd[(size_t)(b * DI + e) * NC + c] = sd;
}

__global__ void scanB_kernel(const float* __restrict__ qbuf,
                             const float* __restrict__ sumd,
                             const float* __restrict__ A_log,
                             float* __restrict__ hin)
{
    int i = blockIdx.x * 256 + threadIdx.x;   // ((b<<10)|e)<<4 | n
    int n = i & 15;
    int e = (i >> 4) & (DI - 1);
    int b = i >> 14;
    float Ae = -__expf(A_log[e * 16 + n]);
    float h = 0.0f;
    size_t base = (size_t)(b * DI + e) * NC;
    for (int c = 0; c < NC; ++c) {
        hin[(base + c) * 16 + n] = h;
        float P = __expf(Ae * sumd[base + c]);
        h = P * h + qbuf[(base + c) * 16 + n];
    }
}

// Pass C: replay from entry state; y (bf16) = (scan + xc*D) * silu(z)
__global__ void scanC_kernel(const float* __restrict__ delta,
                             const float* __restrict__ xc,
                             const float* __restrict__ xdbl,
                             const u16* __restrict__ xz,
                             const float* __restrict__ A_log,
                             const float* __restrict__ Dp,
                             const float* __restrict__ hin,
                             u16* __restrict__ y)
{
    int i = blockIdx.x * 256 + threadIdx.x;
    int e = i & (DI - 1);
    int c = (i >> 10) & (NC - 1);
    int b = i >> 15;
    float Ae[16], h[16];
    size_t base = ((size_t)(b * DI + e) * NC + c) * 16;
    #pragma unroll
    for (int n = 0; n < 16; ++n) {
        Ae[n] = -__expf(A_log[e * 16 + n]);
        h[n] = hin[base + n];
    }
    float Dv = Dp[e];
    int l0 = c * CL;
    for (int l = 0; l < CL; ++l) {
        size_t tok = (size_t)b * LSEQ + l0 + l;
        float d   = delta[tok * DI + e];
        float xcv = xc[tok * DI + e];
        float zv  = bf2f(xz[tok * 2048 + DI + e]);
        float dx = d * xcv;
        const float4* B4 = (const float4*)(xdbl + tok * 64 + 32);
        const float4* C4 = (const float4*)(xdbl + tok * 64 + 48);
        float yv = 0.0f;
        #pragma unroll
        for (int q = 0; q < 4; ++q) {
            float4 Bq = B4[q];
            float4 Cq = C4[q];
            float hb;
            hb = __expf(d * Ae[4*q+0]) * h[4*q+0] + dx * Bq.x; h[4*q+0] = hb; yv = fmaf(hb, Cq.x, yv);
            hb = __expf(d * Ae[4*q+1]) * h[4*q+1] + dx * Bq.y; h[4*q+1] = hb; yv = fmaf(hb, Cq.y, yv);
            hb = __expf(d * Ae[4*q+2]) * h[4*q+2] + dx * Bq.z; h[4*q+2] = hb; yv = fmaf(hb, Cq.z, yv);
            hb = __expf(d * Ae[4*q+3]) * h[4*q+3] + dx * Bq.w; h[4*q+3] = hb; yv = fmaf(hb, Cq.w, yv);
        }
        yv += xcv * Dv;
        yv *= siluf(zv);
        y[tok * DI + e] = f2bf(yv);
    }
}

extern "C" void kernel_launch(void* const* d_in, const int* in_sizes, int n_in,
                              void* d_out, int out_size, void* d_ws, size_t ws_size,
                              hipStream_t stream)
{
    const float* x         = (const float*)d_in[0];
    const float* ln1_g     = (const float*)d_in[1];
    const float* ln1_b     = (const float*)d_in[2];
    const float* in_proj_w = (const float*)d_in[3];
    const float* conv_w    = (const float*)d_in[4];
    const float* conv_b    = (const float*)d_in[5];
    const float* x_proj_w  = (const float*)d_in[6];
    const float* dt_proj_w = (const float*)d_in[7];
    const float* dt_proj_b = (const float*)d_in[8];
    const float* A_log     = (const float*)d_in[9];
    const float* Dp        = (const float*)d_in[10];
    const float* out_proj_w= (const float*)d_in[11];
    const float* ln2_g     = (const float*)d_in[12];
    const float* ln2_b     = (const float*)d_in[13];
    const float* ffn1_w    = (const float*)d_in[14];
    const float* ffn1_b    = (const float*)d_in[15];
    const float* ffn2_w    = (const float*)d_in[16];
    const float* ffn2_b    = (const float*)d_in[17];
    float* out = (float*)d_out;

    // -------- workspace carve (39.75 MB total) --------
    char* wsb = (char*)d_ws;
    u16*   lnb   = (u16*)wsb;    wsb += (size_t)2048 * 512 * 2;   // 2MB  bf16 LN out
    u16*   xzb   = (u16*)wsb;    wsb += (size_t)2048 * 2048 * 2;  // 8MB  bf16 xz; later ffn_mid
    float* xc    = (float*)wsb;  wsb += (size_t)2048 * 1024 * 4;  // 8MB
    float* xdbl  = (float*)wsb;  wsb += (size_t)2048 * 64 * 4;    // 512KB
    float* delta = (float*)wsb;  wsb += (size_t)2048 * 1024 * 4;  // 8MB (holds w_in early)
    float* qbuf  = (float*)wsb;  wsb += (size_t)2048 * NC * 16 * 4; // 4MB (holds y_bf16 later)
    float* x2    = (float*)wsb;  wsb += (size_t)2048 * 512 * 4;   // 4MB (holds hin early)
    float* sumd  = (float*)wsb;  wsb += (size_t)BB * DI * NC * 4; // 256KB
    u16*   w_out = (u16*)wsb;    wsb += (size_t)512 * 1024 * 2;   // 1MB
    u16*   w_f1  = (u16*)wsb;    wsb += (size_t)2048 * 512 * 2;   // 2MB
    u16*   w_f2  = (u16*)wsb;    wsb += (size_t)512 * 2048 * 2;   // 2MB
    u16*   w_in  = (u16*)delta;  // alias: dead before delta written (step 5)
    float* hin   = x2;           // alias: dead before x2 written (step 7)
    u16*   y_us  = (u16*)qbuf;   // alias: q fully consumed by scanB before scanC writes y
    u16*   ffnm  = xzb;          // alias: xz dead after scanC

    dim3 blk32(32, 32);

    // 0) weight conversions to bf16
    cvt_bf16_kernel<<<(2048*512)/1024, 256, 0, stream>>>(in_proj_w, w_in, 2048*512);
    cvt_bf16_kernel<<<(512*1024)/1024, 256, 0, stream>>>(out_proj_w, w_out, 512*1024);
    cvt_bf16_kernel<<<(2048*512)/1024, 256, 0, stream>>>(ffn1_w, w_f1, 2048*512);
    cvt_bf16_kernel<<<(512*2048)/1024, 256, 0, stream>>>(ffn2_w, w_f2, 512*2048);
    // 1) LN1 -> bf16
    ln_bf16_kernel<<<NTOK, 256, 0, stream>>>(x, ln1_g, ln1_b, lnb);
    // 2) in_proj MFMA: [2048,512]x[2048,512]^T -> xz bf16 [2048,2048]
    mgemm_kernel<0,128,128,32,1><<<dim3(16,16), 256, 0, stream>>>(lnb, w_in, 512, xzb, 2048, nullptr, nullptr, 0);
    // 3) conv + silu -> xc fp32
    conv_silu_kernel<<<(NTOK * DI) / 256, 256, 0, stream>>>(xzb, conv_w, conv_b, xc);
    // 4) x_proj fp32: [2048,1024]x[64,1024]^T -> xdbl [2048,64]
    gemm_kernel<0><<<dim3(2, 64), blk32, 0, stream>>>(xc, 1024, x_proj_w, 1024, xdbl, 64, nullptr);
    // 5) dt_proj + softplus: [2048,32]x[1024,32]^T -> delta
    gemm_kernel<1><<<dim3(32, 64), blk32, 0, stream>>>(xdbl, 64, dt_proj_w, 32, delta, 1024, dt_proj_b);
    // 6) chunked scan
    scanA_kernel<<<(BB * NC * DI) / 256, 256, 0, stream>>>(delta, xc, xdbl, A_log, qbuf, sumd);
    scanB_kernel<<<(BB * DI * 16) / 256, 256, 0, stream>>>(qbuf, sumd, A_log, hin);
    scanC_kernel<<<(BB * NC * DI) / 256, 256, 0, stream>>>(delta, xc, xdbl, xzb, A_log, Dp, hin, y_us);
    // 7) out_proj MFMA + residual(x): [2048,1024]x[512,1024]^T -> x2 fp32
    mgemm_kernel<3,64,64,64,0><<<dim3(8,32), 256, 0, stream>>>(y_us, w_out, 1024, x2, 512, nullptr, x, 512);
    // 8) LN2 -> bf16
    ln_bf16_kernel<<<NTOK, 256, 0, stream>>>(x2, ln2_g, ln2_b, lnb);
    // 9) ffn1 MFMA + bias + gelu -> ffn_mid bf16 [2048,2048]
    mgemm_kernel<2,128,128,32,1><<<dim3(16,16), 256, 0, stream>>>(lnb, w_f1, 512, ffnm, 2048, ffn1_b, nullptr, 0);
    // 10) ffn2 MFMA + bias + residual(x2) -> out fp32
    mgemm_kernel<4,64,64,64,0><<<dim3(8,32), 256, 0, stream>>>(ffnm, w_f2, 2048, out, 512, ffn2_b, x2, 512);
}

// Round 4
// 204.726 us; speedup vs baseline: 13.0727x; 1.1846x over previous
//
#include <hip/hip_runtime.h>
#include <cmath>

typedef unsigned short u16;
typedef __attribute__((ext_vector_type(8))) short bf16x8;
typedef __attribute__((ext_vector_type(4))) float f32x4;

#define BB    2
#define LSEQ  1024
#define DM    512
#define DI    1024
#define NTOK  2048   // BB*LSEQ
#define NC    32     // chunks per sequence
#define CL    32     // chunk length

__device__ __forceinline__ float siluf(float x) {
    return x * (1.0f / (1.0f + __expf(-x)));
}
__device__ __forceinline__ float geluf(float x) {
    float c = 0.7978845608028654f * (x + 0.044715f * x * x * x);
    return 0.5f * x * (1.0f + tanhf(c));
}
__device__ __forceinline__ u16 f2bf(float f) {
    union { float f; unsigned u; } v; v.f = f;
    unsigned r = v.u + 0x7fff + ((v.u >> 16) & 1);
    return (u16)(r >> 16);
}
__device__ __forceinline__ float bf2f(u16 u) {
    union { unsigned u; float f; } v; v.u = ((unsigned)u) << 16; return v.f;
}
__device__ __forceinline__ void async_cp16(const u16* g, u16* l) {
    __builtin_amdgcn_global_load_lds(
        (const __attribute__((address_space(1))) void*)g,
        (__attribute__((address_space(3))) void*)l, 16, 0, 0);
}

// ---------------- fused fp32 -> bf16 conversion for all 5 weight tensors ----------------
__global__ void cvt_all_kernel(const float* __restrict__ s0, u16* __restrict__ d0,   // 1048576
                               const float* __restrict__ s1, u16* __restrict__ d1,   // 524288
                               const float* __restrict__ s2, u16* __restrict__ d2,   // 1048576
                               const float* __restrict__ s3, u16* __restrict__ d3,   // 1048576
                               const float* __restrict__ s4, u16* __restrict__ d4)   // 65536
{
    int i = (blockIdx.x * 256 + threadIdx.x) * 4;
    const float* s; u16* d; int off;
    if      (i < 1048576) { s = s0; d = d0; off = i; }
    else if (i < 1572864) { s = s1; d = d1; off = i - 1048576; }
    else if (i < 2621440) { s = s2; d = d2; off = i - 1572864; }
    else if (i < 3670016) { s = s3; d = d3; off = i - 2621440; }
    else if (i < 3735552) { s = s4; d = d4; off = i - 3670016; }
    else return;
    float4 v = *(const float4*)(s + off);
    ushort4 o;
    o.x = f2bf(v.x); o.y = f2bf(v.y); o.z = f2bf(v.z); o.w = f2bf(v.w);
    *(ushort4*)(d + off) = o;
}

// ---------------- LayerNorm: one block (256 thr) per token, D=512; bf16 out ----------------
__global__ void ln_bf16_kernel(const float* __restrict__ x, const float* __restrict__ g,
                               const float* __restrict__ b, u16* __restrict__ out)
{
    int t = blockIdx.x;
    int tid = threadIdx.x;
    const float* xr = x + (size_t)t * DM;
    float v0 = xr[tid];
    float v1 = xr[tid + 256];
    float s  = v0 + v1;
    float s2 = v0 * v0 + v1 * v1;
    #pragma unroll
    for (int o = 32; o > 0; o >>= 1) { s += __shfl_down(s, o); s2 += __shfl_down(s2, o); }
    __shared__ float sh[4], sh2[4];
    __shared__ float smu, srs;
    int wid = tid >> 6, lane = tid & 63;
    if (lane == 0) { sh[wid] = s; sh2[wid] = s2; }
    __syncthreads();
    if (tid == 0) {
        float a  = sh[0] + sh[1] + sh[2] + sh[3];
        float a2 = sh2[0] + sh2[1] + sh2[2] + sh2[3];
        float mu = a / DM;
        float var = a2 / DM - mu * mu;
        smu = mu;
        srs = rsqrtf(var + 1e-5f);
    }
    __syncthreads();
    float mu = smu, rs = srs;
    u16* orow = out + (size_t)t * DM;
    orow[tid]       = f2bf((v0 - mu) * rs * g[tid]       + b[tid]);
    orow[tid + 256] = f2bf((v1 - mu) * rs * g[tid + 256] + b[tid + 256]);
}

// ---------------- MFMA bf16 GEMM: C[m,n] = epi( sum_k A[m,k]*W[n,k] ) ----------------
// EPI: 0 plain, 2 bias+gelu, 3 +resid, 4 bias+resid.  OBF: bf16 output.
template<int EPI, int BM, int BN, int BK, int OBF>
__global__ __launch_bounds__(256)
void mgemm_kernel(const u16* __restrict__ A, const u16* __restrict__ W, int K,
                  void* __restrict__ Cp, int ldc,
                  const float* __restrict__ bias, const float* __restrict__ resid, int ldr)
{
    __shared__ u16 As[BM * BK];
    __shared__ u16 Bs[BN * BK];
    constexpr int WR = BM / 2, WC = BN / 2;
    constexpr int MR = WR / 16, NR = WC / 16;
    constexpr int LPR = BK / 8;            // lanes per staged row (16B each)
    constexpr int CH_ROWS = 64 / LPR;      // rows per 1KB chunk
    constexpr int NCH_A = BM / CH_ROWS, NCH_B = BN / CH_ROWS;

    const int tid = threadIdx.x;
    const int wave = tid >> 6, lane = tid & 63;
    const int wm = wave >> 1, wn = wave & 1;
    const int m0 = blockIdx.y * BM, n0 = blockIdx.x * BN;
    const int crow = lane / LPR, ckoff = (lane % LPR) * 8;
    const int fr = lane & 15;

    f32x4 acc[MR][NR] = {};

    for (int k0 = 0; k0 < K; k0 += BK) {
        for (int c = wave; c < NCH_A; c += 4) {
            const u16* g = A + (size_t)(m0 + c * CH_ROWS + crow) * K + k0 + ckoff;
            async_cp16(g, &As[c * 512]);
        }
        for (int c = wave; c < NCH_B; c += 4) {
            const u16* g = W + (size_t)(n0 + c * CH_ROWS + crow) * K + k0 + ckoff;
            async_cp16(g, &Bs[c * 512]);
        }
        __syncthreads();
        #pragma unroll
        for (int ks = 0; ks < BK / 32; ++ks) {
            const int fk = ks * 32 + ((lane >> 4) << 3);
            bf16x8 af[MR], bv[NR];
            #pragma unroll
            for (int i = 0; i < MR; ++i)
                af[i] = *(const bf16x8*)&As[(wm * WR + i * 16 + fr) * BK + fk];
            #pragma unroll
            for (int j = 0; j < NR; ++j)
                bv[j] = *(const bf16x8*)&Bs[(wn * WC + j * 16 + fr) * BK + fk];
            #pragma unroll
            for (int i = 0; i < MR; ++i)
                #pragma unroll
                for (int j = 0; j < NR; ++j)
                    acc[i][j] = __builtin_amdgcn_mfma_f32_16x16x32_bf16(af[i], bv[j], acc[i][j], 0, 0, 0);
        }
        __syncthreads();
    }

    // C/D layout (m89-verified): col = lane&15, row = (lane>>4)*4 + reg
    const int rbase = (lane >> 4) << 2;
    #pragma unroll
    for (int i = 0; i < MR; ++i) {
        #pragma unroll
        for (int j = 0; j < NR; ++j) {
            const int col  = n0 + wn * WC + j * 16 + fr;
            const int row0 = m0 + wm * WR + i * 16 + rbase;
            float bvv = (EPI == 2 || EPI == 4) ? bias[col] : 0.0f;
            #pragma unroll
            for (int r = 0; r < 4; ++r) {
                float v = acc[i][j][r];
                if (EPI == 2) v = geluf(v + bvv);
                if (EPI == 3) v += resid[(size_t)(row0 + r) * ldr + col];
                if (EPI == 4) v += bvv + resid[(size_t)(row0 + r) * ldr + col];
                if (OBF) ((u16*)Cp)[(size_t)(row0 + r) * ldc + col] = f2bf(v);
                else     ((float*)Cp)[(size_t)(row0 + r) * ldc + col] = v;
            }
        }
    }
}

// ---------------- x_proj split-K MFMA: P[ks][2048][64] partials ----------------
// A = xcb [2048,1024] bf16, W = w_x [64,1024] bf16. 8 K-slices of 128.
__global__ __launch_bounds__(256)
void xproj_part_kernel(const u16* __restrict__ A, const u16* __restrict__ W,
                       float* __restrict__ P)
{
    constexpr int BM = 64, BN = 64, BK = 128;
    __shared__ u16 As[BM * BK];
    __shared__ u16 Bs[BN * BK];
    const int tid = threadIdx.x;
    const int wave = tid >> 6, lane = tid & 63;
    const int wm = wave >> 1, wn = wave & 1;
    const int ks = blockIdx.x;               // 0..7
    const int m0 = blockIdx.y * BM;
    const int k0 = ks * BK;
    const int crow = lane >> 4, ckoff = (lane & 15) * 8;   // 16 lanes/row, 4 rows/chunk
    const int fr = lane & 15;

    for (int c = wave; c < 16; c += 4) {
        async_cp16(A + (size_t)(m0 + c * 4 + crow) * 1024 + k0 + ckoff, &As[c * 512]);
        async_cp16(W + (size_t)(c * 4 + crow) * 1024 + k0 + ckoff, &Bs[c * 512]);
    }
    __syncthreads();

    f32x4 acc[2][2] = {};
    #pragma unroll
    for (int ks2 = 0; ks2 < 4; ++ks2) {
        const int fk = ks2 * 32 + ((lane >> 4) << 3);
        bf16x8 af[2], bv[2];
        #pragma unroll
        for (int i = 0; i < 2; ++i)
            af[i] = *(const bf16x8*)&As[(wm * 32 + i * 16 + fr) * BK + fk];
        #pragma unroll
        for (int j = 0; j < 2; ++j)
            bv[j] = *(const bf16x8*)&Bs[(wn * 32 + j * 16 + fr) * BK + fk];
        #pragma unroll
        for (int i = 0; i < 2; ++i)
            #pragma unroll
            for (int j = 0; j < 2; ++j)
                acc[i][j] = __builtin_amdgcn_mfma_f32_16x16x32_bf16(af[i], bv[j], acc[i][j], 0, 0, 0);
    }

    const int rbase = (lane >> 4) << 2;
    float* Pk = P + (size_t)ks * NTOK * 64;
    #pragma unroll
    for (int i = 0; i < 2; ++i)
        #pragma unroll
        for (int j = 0; j < 2; ++j) {
            const int col  = wn * 32 + j * 16 + fr;
            const int row0 = m0 + wm * 32 + i * 16 + rbase;
            #pragma unroll
            for (int r = 0; r < 4; ++r)
                Pk[(size_t)(row0 + r) * 64 + col] = acc[i][j][r];
        }
}

__global__ void xproj_reduce_kernel(const float* __restrict__ P, float* __restrict__ xdbl)
{
    int i = blockIdx.x * 256 + threadIdx.x;   // over 2048*64
    float s = 0.0f;
    #pragma unroll
    for (int ks = 0; ks < 8; ++ks) s += P[(size_t)ks * NTOK * 64 + i];
    xdbl[i] = s;
}

// ---------------- fp32 GEMM (dt_proj) ----------------
// EPI: 1 bias+softplus
template<int EPI>
__global__ __launch_bounds__(1024)
void gemm_kernel(const float* __restrict__ A, int lda,
                 const float* __restrict__ W, int K,
                 float* __restrict__ C, int ldc,
                 const float* __restrict__ bias)
{
    __shared__ float As[32][33];
    __shared__ float Ws[32][33];
    int tx = threadIdx.x, ty = threadIdx.y;
    int m0 = blockIdx.y * 32, n0 = blockIdx.x * 32;
    float acc = 0.0f;
    for (int k0 = 0; k0 < K; k0 += 32) {
        As[ty][tx] = A[(size_t)(m0 + ty) * lda + k0 + tx];
        Ws[ty][tx] = W[(size_t)(n0 + ty) * K  + k0 + tx];
        __syncthreads();
        #pragma unroll
        for (int kk = 0; kk < 32; ++kk)
            acc = fmaf(As[ty][kk], Ws[tx][kk], acc);
        __syncthreads();
    }
    int m = m0 + ty, n = n0 + tx;
    float v = acc;
    if (EPI == 1) { v += bias[n]; v = (v < 20.0f) ? log1pf(__expf(v)) : v; }
    C[(size_t)m * ldc + n] = v;
}

// ---------------- depthwise causal conv1d (width 4) + SiLU; bf16 in, fp32+bf16 out ----------------
__global__ void conv_silu_kernel(const u16* __restrict__ xz,
                                 const float* __restrict__ cw,
                                 const float* __restrict__ cb,
                                 float* __restrict__ xc,
                                 u16* __restrict__ xcb)
{
    int idx = blockIdx.x * 256 + threadIdx.x;   // over NTOK*DI
    int e = idx & (DI - 1);
    int t = idx >> 10;
    int l = t & (LSEQ - 1);
    float w0 = cw[e * 4 + 0], w1 = cw[e * 4 + 1], w2 = cw[e * 4 + 2], w3 = cw[e * 4 + 3];
    float acc = cb[e];
    const u16* base = xz + (size_t)t * 2048 + e;
    if (l >= 3) acc = fmaf(bf2f(base[-3 * 2048]), w0, acc);
    if (l >= 2) acc = fmaf(bf2f(base[-2 * 2048]), w1, acc);
    if (l >= 1) acc = fmaf(bf2f(base[-1 * 2048]), w2, acc);
    acc = fmaf(bf2f(base[0]), w3, acc);
    float v = siluf(acc);
    xc[idx] = v;
    xcb[idx] = f2bf(v);
}

// ============ chunked selective scan ============
__global__ void scanA_kernel(const float* __restrict__ delta,
                             const float* __restrict__ xc,
                             const float* __restrict__ xdbl,
                             const float* __restrict__ A_log,
                             float* __restrict__ qbuf,
                             float* __restrict__ sumd)
{
    int i = blockIdx.x * 256 + threadIdx.x;   // ((b*NC + c) << 10) | e
    int e = i & (DI - 1);
    int c = (i >> 10) & (NC - 1);
    int b = i >> 15;
    float Ae[16], h[16];
    #pragma unroll
    for (int n = 0; n < 16; ++n) { Ae[n] = -__expf(A_log[e * 16 + n]); h[n] = 0.0f; }
    float sd = 0.0f;
    int l0 = c * CL;
    for (int l = 0; l < CL; ++l) {
        size_t tok = (size_t)b * LSEQ + l0 + l;
        float d   = delta[tok * DI + e];
        float xcv = xc[tok * DI + e];
        sd += d;
        float dx = d * xcv;
        const float4* B4 = (const float4*)(xdbl + tok * 64 + 32);
        #pragma unroll
        for (int q = 0; q < 4; ++q) {
            float4 Bq = B4[q];
            h[4*q+0] = __expf(d * Ae[4*q+0]) * h[4*q+0] + dx * Bq.x;
            h[4*q+1] = __expf(d * Ae[4*q+1]) * h[4*q+1] + dx * Bq.y;
            h[4*q+2] = __expf(d * Ae[4*q+2]) * h[4*q+2] + dx * Bq.z;
            h[4*q+3] = __expf(d * Ae[4*q+3]) * h[4*q+3] + dx * Bq.w;
        }
    }
    size_t base = ((size_t)(b * DI + e) * NC + c) * 16;
    #pragma unroll
    for (int n = 0; n < 16; ++n) qbuf[base + n] = h[n];
    sumd[(size_t)(b * DI + e) * NC + c] = sd;
}

__global__ void scanB_kernel(const float* __restrict__ qbuf,
                             const float* __restrict__ sumd,
                             const float* __restrict__ A_log,
                             float* __restrict__ hin)
{
    int i = blockIdx.x * 256 + threadIdx.x;   // ((b<<10)|e)<<4 | n
    int n = i & 15;
    int e = (i >> 4) & (DI - 1);
    int b = i >> 14;
    float Ae = -__expf(A_log[e * 16 + n]);
    float h = 0.0f;
    size_t base = (size_t)(b * DI + e) * NC;
    for (int c = 0; c < NC; ++c) {
        hin[(base + c) * 16 + n] = h;
        float P = __expf(Ae * sumd[base + c]);
        h = P * h + qbuf[(base + c) * 16 + n];
    }
}

// Pass C: replay from entry state; y (bf16) = (scan + xc*D) * silu(z)
__global__ void scanC_kernel(const float* __restrict__ delta,
                             const float* __restrict__ xc,
                             const float* __restrict__ xdbl,
                             const u16* __restrict__ xz,
                             const float* __restrict__ A_log,
                             const float* __restrict__ Dp,
                             const float* __restrict__ hin,
                             u16* __restrict__ y)
{
    int i = blockIdx.x * 256 + threadIdx.x;
    int e = i & (DI - 1);
    int c = (i >> 10) & (NC - 1);
    int b = i >> 15;
    float Ae[16], h[16];
    size_t base = ((size_t)(b * DI + e) * NC + c) * 16;
    #pragma unroll
    for (int n = 0; n < 16; ++n) {
        Ae[n] = -__expf(A_log[e * 16 + n]);
        h[n] = hin[base + n];
    }
    float Dv = Dp[e];
    int l0 = c * CL;
    for (int l = 0; l < CL; ++l) {
        size_t tok = (size_t)b * LSEQ + l0 + l;
        float d   = delta[tok * DI + e];
        float xcv = xc[tok * DI + e];
        float zv  = bf2f(xz[tok * 2048 + DI + e]);
        float dx = d * xcv;
        const float4* B4 = (const float4*)(xdbl + tok * 64 + 32);
        const float4* C4 = (const float4*)(xdbl + tok * 64 + 48);
        float yv = 0.0f;
        #pragma unroll
        for (int q = 0; q < 4; ++q) {
            float4 Bq = B4[q];
            float4 Cq = C4[q];
            float hb;
            hb = __expf(d * Ae[4*q+0]) * h[4*q+0] + dx * Bq.x; h[4*q+0] = hb; yv = fmaf(hb, Cq.x, yv);
            hb = __expf(d * Ae[4*q+1]) * h[4*q+1] + dx * Bq.y; h[4*q+1] = hb; yv = fmaf(hb, Cq.y, yv);
            hb = __expf(d * Ae[4*q+2]) * h[4*q+2] + dx * Bq.z; h[4*q+2] = hb; yv = fmaf(hb, Cq.z, yv);
            hb = __expf(d * Ae[4*q+3]) * h[4*q+3] + dx * Bq.w; h[4*q+3] = hb; yv = fmaf(hb, Cq.w, yv);
        }
        yv += xcv * Dv;
        yv *= siluf(zv);
        y[tok * DI + e] = f2bf(yv);
    }
}

extern "C" void kernel_launch(void* const* d_in, const int* in_sizes, int n_in,
                              void* d_out, int out_size, void* d_ws, size_t ws_size,
                              hipStream_t stream)
{
    const float* x         = (const float*)d_in[0];
    const float* ln1_g     = (const float*)d_in[1];
    const float* ln1_b     = (const float*)d_in[2];
    const float* in_proj_w = (const float*)d_in[3];
    const float* conv_w    = (const float*)d_in[4];
    const float* conv_b    = (const float*)d_in[5];
    const float* x_proj_w  = (const float*)d_in[6];
    const float* dt_proj_w = (const float*)d_in[7];
    const float* dt_proj_b = (const float*)d_in[8];
    const float* A_log     = (const float*)d_in[9];
    const float* Dp        = (const float*)d_in[10];
    const float* out_proj_w= (const float*)d_in[11];
    const float* ln2_g     = (const float*)d_in[12];
    const float* ln2_b     = (const float*)d_in[13];
    const float* ffn1_w    = (const float*)d_in[14];
    const float* ffn1_b    = (const float*)d_in[15];
    const float* ffn2_w    = (const float*)d_in[16];
    const float* ffn2_b    = (const float*)d_in[17];
    float* out = (float*)d_out;

    // -------- workspace carve (~44 MB) --------
    char* wsb = (char*)d_ws;
    u16*   lnb   = (u16*)wsb;    wsb += (size_t)2048 * 512 * 2;     // 2MB  bf16 LN out
    u16*   xzb   = (u16*)wsb;    wsb += (size_t)2048 * 2048 * 2;    // 8MB  bf16 xz; later ffn_mid
    float* xc    = (float*)wsb;  wsb += (size_t)2048 * 1024 * 4;    // 8MB
    u16*   xcb   = (u16*)wsb;    wsb += (size_t)2048 * 1024 * 2;    // 4MB  bf16 xc
    float* xdbl  = (float*)wsb;  wsb += (size_t)2048 * 64 * 4;      // 512KB
    float* delta = (float*)wsb;  wsb += (size_t)2048 * 1024 * 4;    // 8MB (holds w_in early)
    float* qbuf  = (float*)wsb;  wsb += (size_t)2048 * NC * 16 * 4; // 4MB (P early, y_bf16 late)
    float* x2    = (float*)wsb;  wsb += (size_t)2048 * 512 * 4;     // 4MB (holds hin early)
    float* sumd  = (float*)wsb;  wsb += (size_t)BB * DI * NC * 4;   // 256KB
    u16*   w_out = (u16*)wsb;    wsb += (size_t)512 * 1024 * 2;     // 1MB
    u16*   w_f1  = (u16*)wsb;    wsb += (size_t)2048 * 512 * 2;     // 2MB
    u16*   w_f2  = (u16*)wsb;    wsb += (size_t)512 * 2048 * 2;     // 2MB
    u16*   w_x   = (u16*)wsb;    wsb += (size_t)64 * 1024 * 2;      // 128KB
    u16*   w_in  = (u16*)delta;  // alias: dead before delta written (step 5)
    float* Ppart = qbuf;         // alias: consumed by reduce before scanA writes qbuf
    float* hin   = x2;           // alias: dead before x2 written (step 7)
    u16*   y_us  = (u16*)qbuf;   // alias: qbuf consumed by scanB before scanC writes y
    u16*   ffnm  = xzb;          // alias: xz dead after scanC

    // 0) weight conversions to bf16 (one kernel)
    cvt_all_kernel<<<3648, 256, 0, stream>>>(in_proj_w, w_in, out_proj_w, w_out,
                                             ffn1_w, w_f1, ffn2_w, w_f2, x_proj_w, w_x);
    // 1) LN1 -> bf16
    ln_bf16_kernel<<<NTOK, 256, 0, stream>>>(x, ln1_g, ln1_b, lnb);
    // 2) in_proj MFMA: [2048,512]x[2048,512]^T -> xz bf16 [2048,2048]
    mgemm_kernel<0,128,128,32,1><<<dim3(16,16), 256, 0, stream>>>(lnb, w_in, 512, xzb, 2048, nullptr, nullptr, 0);
    // 3) conv + silu -> xc fp32 + xcb bf16
    conv_silu_kernel<<<(NTOK * DI) / 256, 256, 0, stream>>>(xzb, conv_w, conv_b, xc, xcb);
    // 4) x_proj split-K MFMA + reduce -> xdbl fp32 [2048,64]
    xproj_part_kernel<<<dim3(8, 32), 256, 0, stream>>>(xcb, w_x, Ppart);
    xproj_reduce_kernel<<<(NTOK * 64) / 256, 256, 0, stream>>>(Ppart, xdbl);
    // 5) dt_proj + softplus: [2048,32]x[1024,32]^T -> delta
    gemm_kernel<1><<<dim3(32, 64), dim3(32, 32), 0, stream>>>(xdbl, 64, dt_proj_w, 32, delta, 1024, dt_proj_b);
    // 6) chunked scan
    scanA_kernel<<<(BB * NC * DI) / 256, 256, 0, stream>>>(delta, xc, xdbl, A_log, qbuf, sumd);
    scanB_kernel<<<(BB * DI * 16) / 256, 256, 0, stream>>>(qbuf, sumd, A_log, hin);
    scanC_kernel<<<(BB * NC * DI) / 256, 256, 0, stream>>>(delta, xc, xdbl, xzb, A_log, Dp, hin, y_us);
    // 7) out_proj MFMA + residual(x): [2048,1024]x[512,1024]^T -> x2 fp32
    mgemm_kernel<3,64,64,64,0><<<dim3(8,32), 256, 0, stream>>>(y_us, w_out, 1024, x2, 512, nullptr, x, 512);
    // 8) LN2 -> bf16
    ln_bf16_kernel<<<NTOK, 256, 0, stream>>>(x2, ln2_g, ln2_b, lnb);
    // 9) ffn1 MFMA + bias + gelu -> ffn_mid bf16 [2048,2048]
    mgemm_kernel<2,128,128,32,1><<<dim3(16,16), 256, 0, stream>>>(lnb, w_f1, 512, ffnm, 2048, ffn1_b, nullptr, 0);
    // 10) ffn2 MFMA + bias + residual(x2) -> out fp32
    mgemm_kernel<4,64,64,64,0><<<dim3(8,32), 256, 0, stream>>>(ffnm, w_f2, 2048, out, 512, ffn2_b, x2, 512);
}